// Round 6
// baseline (1891.348 us; speedup 1.0000x reference)
//
#include <hip/hip_runtime.h>
#include <cstdint>

#define Eexp 8
#define Bb   16384
#define Dd   512
#define Hh   512
#define Zz   64

typedef _Float16 f16x8 __attribute__((ext_vector_type(8)));
typedef float    f32x4 __attribute__((ext_vector_type(4)));

// fragment-major (fm) layout: per (tile=row/16, kb=k/32) a 1024-f16 block:
//   [hi 512 | lo 512]; lane l owns 8 f16 at l*8 (+512 for lo):
//   element j = M[tile*16 + (l&15)][kb*32 + (l>>4)*8 + j]
// per-expert weight region offsets (f16 elems)
#define OFF_ENCIN  0
#define OFF_HID0   524288
#define OFF_HID1   1048576
#define OFF_HEADS  1572864
#define OFF_DECIN  1703936
#define OFF_DHID0  1769472
#define OFF_DHID1  2293760
#define OFF_DECOUT 2818048
#define PEREXP     3342336
#define WT_TOTAL   (8 * (size_t)PEREXP)

// ---------------------------------------------------------------------------
// fp32 src -> fragment-major split-f16.  TR=true: src[K,N] (weights, transpose)
// TR=false: src[M,K] (activations). grid (outer/64, K/64, E).
// ---------------------------------------------------------------------------
template<bool TR>
__global__ __launch_bounds__(256)
void fmsplit(const float* __restrict__ src, _Float16* __restrict__ dst,
             int KTOT, int inner, long sStride, long dStride)
{
    __shared__ float t[64][65];
    const int e  = blockIdx.z;
    const int o0 = blockIdx.x * 64;     // outer: N (TR) or M
    const int k0 = blockIdx.y * 64;
    const float* S = src + (size_t)e * sStride;
    _Float16*    D = dst + (size_t)e * dStride;
    const int tid = threadIdx.x;
    const int rr = tid >> 4, c4 = (tid & 15) * 4;
    #pragma unroll
    for (int p = 0; p < 4; ++p) {
        const int r = rr + p * 16;
        const float4 v = *reinterpret_cast<const float4*>(
            S + (size_t)(TR ? (k0 + r) : (o0 + r)) * inner + (TR ? o0 : k0) + c4);
        t[r][c4 + 0] = v.x; t[r][c4 + 1] = v.y;
        t[r][c4 + 2] = v.z; t[r][c4 + 3] = v.w;
    }
    __syncthreads();
    const int lane = tid & 63, wid = tid >> 6;
    #pragma unroll
    for (int p = 0; p < 2; ++p) {
        const int g  = wid * 2 + p;          // 0..7
        const int ot = g >> 1, kb = g & 1;
        const int ridx  = ot * 16 + (lane & 15);
        const int kbase = kb * 32 + (lane >> 4) * 8;
        f16x8 hv, lvv;
        #pragma unroll
        for (int j = 0; j < 8; ++j) {
            const float v = TR ? t[kbase + j][ridx] : t[ridx][kbase + j];
            const _Float16 h = (_Float16)v;
            hv[j]  = h;
            lvv[j] = (_Float16)(v - (float)h);
        }
        const size_t base =
            ((size_t)((o0 >> 4) + ot) * (KTOT >> 5) + (k0 >> 5) + kb) * 1024;
        *reinterpret_cast<f16x8*>(D + base + lane * 8)       = hv;
        *reinterpret_cast<f16x8*>(D + base + 512 + lane * 8) = lvv;
    }
}

// ---------------------------------------------------------------------------
// z = mu + exp(0.5*logvar)*eps  (row-major fp32 in) -> fragment-major split
// grid (B/64). K=64.
// ---------------------------------------------------------------------------
__global__ __launch_bounds__(256)
void zfm_kernel(const float* __restrict__ mu, const float* __restrict__ lv,
                const float* __restrict__ eps, _Float16* __restrict__ zfm)
{
    __shared__ float t[64][65];
    const int r0 = blockIdx.x * 64;
    const int tid = threadIdx.x, rr = tid >> 4, c4 = (tid & 15) * 4;
    #pragma unroll
    for (int p = 0; p < 4; ++p) {
        const int r = rr + p * 16;
        const size_t o = (size_t)(r0 + r) * 64 + c4;
        const float4 m = *reinterpret_cast<const float4*>(mu + o);
        const float4 l = *reinterpret_cast<const float4*>(lv + o);
        const float4 e = *reinterpret_cast<const float4*>(eps + o);
        t[r][c4 + 0] = m.x + expf(0.5f * l.x) * e.x;
        t[r][c4 + 1] = m.y + expf(0.5f * l.y) * e.y;
        t[r][c4 + 2] = m.z + expf(0.5f * l.z) * e.z;
        t[r][c4 + 3] = m.w + expf(0.5f * l.w) * e.w;
    }
    __syncthreads();
    const int lane = tid & 63, wid = tid >> 6;
    #pragma unroll
    for (int p = 0; p < 2; ++p) {
        const int g  = wid * 2 + p;
        const int ot = g >> 1, kb = g & 1;
        const int ridx  = ot * 16 + (lane & 15);
        const int kbase = kb * 32 + (lane >> 4) * 8;
        f16x8 hv, lvv;
        #pragma unroll
        for (int j = 0; j < 8; ++j) {
            const float v = t[ridx][kbase + j];
            const _Float16 h = (_Float16)v;
            hv[j]  = h;
            lvv[j] = (_Float16)(v - (float)h);
        }
        const size_t base = ((size_t)((r0 >> 4) + ot) * 2 + kb) * 1024;
        *reinterpret_cast<f16x8*>(zfm + base + lane * 8)       = hv;
        *reinterpret_cast<f16x8*>(zfm + base + 512 + lane * 8) = lvv;
    }
}

// ---------------------------------------------------------------------------
// Zero-LDS split-f16 MFMA GEMM. 256 thr, 4 waves (2x2), wave tile 64x64.
// Operands loaded fragment-major direct global->VGPR (fully coalesced 16B).
// MODE 0: relu -> fragment-major split out (32 KB XOR-swizzled LDS bounce)
// MODE 1: fp32 row-major out + fused per-row SSE partials -> rec8
// MODE 2: heads N=128: wc=0 -> mu(Cf,bias0), wc=1 -> lv(Cf1,bias1)
// ---------------------------------------------------------------------------
template<int KA, int MODE>
__global__ __launch_bounds__(256, 3)
void gemm6(const _Float16* __restrict__ Afm, const _Float16* __restrict__ Wfm,
           const float* __restrict__ bias0, const float* __restrict__ bias1,
           float* __restrict__ Cf, float* __restrict__ Cf1,
           _Float16* __restrict__ Cfm,
           const float* __restrict__ Xin, float* __restrict__ rec8)
{
    constexpr int nY = (MODE == 2) ? 1 : 4;
    constexpr int KB = KA / 32;
    __shared__ uint32_t sb[(MODE == 0) ? 2 * 4096 : 64];

    int wg = blockIdx.x;
    wg = (wg & 7) * ((int)gridDim.x >> 3) + (wg >> 3);   // bijective XCD swizzle
    const int bx = wg / nY, by = wg % nY;

    const int lane = threadIdx.x & 63, wid = threadIdx.x >> 6;
    const int wr = wid >> 1, wc = wid & 1;
    const int row0 = bx * 128, col0 = by * 128;
    const int rt0 = (row0 >> 4) + wr * 4;
    const int ct0 = (col0 >> 4) + wc * 4;

    const _Float16* aBase = Afm + (size_t)rt0 * KB * 1024 + lane * 8;
    const _Float16* wBase = Wfm + (size_t)ct0 * KB * 1024 + lane * 8;

    f32x4 acc[4][4];
    #pragma unroll
    for (int i = 0; i < 4; ++i)
        #pragma unroll
        for (int j = 0; j < 4; ++j) acc[i][j] = {0.f, 0.f, 0.f, 0.f};

    for (int kb = 0; kb < KB; ++kb) {
        f16x8 ah[4], al[4], wh[4], wl[4];
        #pragma unroll
        for (int mf = 0; mf < 4; ++mf) {
            const _Float16* p = aBase + ((size_t)mf * KB + kb) * 1024;
            ah[mf] = *reinterpret_cast<const f16x8*>(p);
            al[mf] = *reinterpret_cast<const f16x8*>(p + 512);
        }
        #pragma unroll
        for (int nf = 0; nf < 4; ++nf) {
            const _Float16* p = wBase + ((size_t)nf * KB + kb) * 1024;
            wh[nf] = *reinterpret_cast<const f16x8*>(p);
            wl[nf] = *reinterpret_cast<const f16x8*>(p + 512);
        }
        #pragma unroll
        for (int mf = 0; mf < 4; ++mf)
            #pragma unroll
            for (int nf = 0; nf < 4; ++nf) {
                acc[mf][nf] = __builtin_amdgcn_mfma_f32_16x16x32_f16(
                    ah[mf], wh[nf], acc[mf][nf], 0, 0, 0);
                acc[mf][nf] = __builtin_amdgcn_mfma_f32_16x16x32_f16(
                    ah[mf], wl[nf], acc[mf][nf], 0, 0, 0);
                acc[mf][nf] = __builtin_amdgcn_mfma_f32_16x16x32_f16(
                    al[mf], wh[nf], acc[mf][nf], 0, 0, 0);
            }
    }

    if (MODE == 0) {
        // two-phase 32 KB bounce -> fragment-major store (XOR chunk swizzle)
        #pragma unroll
        for (int p = 0; p < 2; ++p) {
            if (wc == p) {
                #pragma unroll
                for (int nf = 0; nf < 4; ++nf) {
                    const int col = nf * 16 + (lane & 15);       // 0..63
                    const float bv = bias0[col0 + wc * 64 + col];
                    #pragma unroll
                    for (int mf = 0; mf < 4; ++mf)
                        #pragma unroll
                        for (int j = 0; j < 4; ++j) {
                            const int lrow = mf * 16 + (lane >> 4) * 4 + j;
                            const float v = fmaxf(acc[mf][nf][j] + bv, 0.f);
                            const _Float16 h = (_Float16)v;
                            const _Float16 l = (_Float16)(v - (float)h);
                            const uint32_t pk =
                                (uint32_t)__builtin_bit_cast(uint16_t, h) |
                                ((uint32_t)__builtin_bit_cast(uint16_t, l) << 16);
                            const int chunk = (col >> 2) ^ (lrow & 15);
                            sb[wr * 4096 + lrow * 64 + chunk * 4 + (col & 3)] = pk;
                        }
                }
            }
            __syncthreads();
            if (wc == p) {
                #pragma unroll
                for (int t4 = 0; t4 < 4; ++t4)
                    #pragma unroll
                    for (int kb2 = 0; kb2 < 2; ++kb2) {
                        const int lrow = t4 * 16 + (lane & 15);
                        uint32_t u[8];
                        #pragma unroll
                        for (int jb = 0; jb < 2; ++jb) {
                            const int chunk =
                                (kb2 * 8 + (lane >> 4) * 2 + jb) ^ (lrow & 15);
                            const uint32_t* pp =
                                &sb[wr * 4096 + lrow * 64 + chunk * 4];
                            u[jb * 4 + 0] = pp[0]; u[jb * 4 + 1] = pp[1];
                            u[jb * 4 + 2] = pp[2]; u[jb * 4 + 3] = pp[3];
                        }
                        f16x8 hv, lvv;
                        #pragma unroll
                        for (int j = 0; j < 8; ++j) {
                            hv[j]  = __builtin_bit_cast(_Float16, (uint16_t)(u[j] & 0xffff));
                            lvv[j] = __builtin_bit_cast(_Float16, (uint16_t)(u[j] >> 16));
                        }
                        const int gtile = (row0 >> 4) + wr * 4 + t4;
                        const int gkb   = (col0 >> 5) + wc * 2 + kb2;
                        const size_t base = ((size_t)gtile * 16 + gkb) * 1024;
                        *reinterpret_cast<f16x8*>(Cfm + base + lane * 8)       = hv;
                        *reinterpret_cast<f16x8*>(Cfm + base + 512 + lane * 8) = lvv;
                    }
            }
            __syncthreads();
        }
    } else if (MODE == 1) {
        float rsum[4][4];
        #pragma unroll
        for (int mf = 0; mf < 4; ++mf)
            #pragma unroll
            for (int j = 0; j < 4; ++j) rsum[mf][j] = 0.f;
        #pragma unroll
        for (int nf = 0; nf < 4; ++nf) {
            const int col = col0 + wc * 64 + nf * 16 + (lane & 15);
            const float bv = bias0[col];
            #pragma unroll
            for (int mf = 0; mf < 4; ++mf)
                #pragma unroll
                for (int j = 0; j < 4; ++j) {
                    const int row = row0 + wr * 64 + mf * 16 + (lane >> 4) * 4 + j;
                    const float v = acc[mf][nf][j] + bv;
                    Cf[(size_t)row * 512 + col] = v;
                    const float d = v - Xin[(size_t)row * 512 + col];
                    rsum[mf][j] += d * d;
                }
        }
        #pragma unroll
        for (int mf = 0; mf < 4; ++mf)
            #pragma unroll
            for (int j = 0; j < 4; ++j) {
                float s = rsum[mf][j];
                s += __shfl_xor(s, 1); s += __shfl_xor(s, 2);
                s += __shfl_xor(s, 4); s += __shfl_xor(s, 8);
                if ((lane & 15) == 0) {
                    const int row = row0 + wr * 64 + mf * 16 + (lane >> 4) * 4 + j;
                    rec8[(size_t)(by * 2 + wc) * Bb + row] = s;
                }
            }
    } else {   // MODE 2
        #pragma unroll
        for (int nf = 0; nf < 4; ++nf) {
            const int colq = wc * 64 + nf * 16 + (lane & 15);    // 0..127
            const float bv = (colq < 64) ? bias0[colq] : bias1[colq - 64];
            float* CP = (colq < 64) ? Cf : Cf1;
            const int c = colq & 63;
            #pragma unroll
            for (int mf = 0; mf < 4; ++mf)
                #pragma unroll
                for (int j = 0; j < 4; ++j) {
                    const int row = row0 + wr * 64 + mf * 16 + (lane >> 4) * 4 + j;
                    CP[(size_t)row * 64 + c] = acc[mf][nf][j] + bv;
                }
        }
    }
}

// sum 8 partials, running-min select + gather
__global__ __launch_bounds__(256)
void select_kernel(const float* __restrict__ rec8, float* __restrict__ best,
                   const float* __restrict__ mu_e, const float* __restrict__ lv_e,
                   const float* __restrict__ xhat,
                   float* __restrict__ out_mu, float* __restrict__ out_lv,
                   float* __restrict__ out_xh, int isFirst)
{
    const int wave = threadIdx.x >> 6;
    const int lane = threadIdx.x & 63;
    const int row  = blockIdx.x * 4 + wave;
    float r = 0.f;
    #pragma unroll
    for (int p = 0; p < 8; ++p) r += rec8[(size_t)p * Bb + row];
    r *= (1.0f / 512.0f);
    const bool cond = isFirst || (r < best[row]);
    if (cond) {
        if (lane == 0) best[row] = r;
        out_mu[(size_t)row * Zz + lane] = mu_e[(size_t)row * Zz + lane];
        out_lv[(size_t)row * Zz + lane] = lv_e[(size_t)row * Zz + lane];
        const float4* src = reinterpret_cast<const float4*>(&xhat[(size_t)row * Dd]);
        float4*       dst = reinterpret_cast<float4*>(&out_xh[(size_t)row * Dd]);
        dst[lane]      = src[lane];
        dst[lane + 64] = src[lane + 64];
    }
}

extern "C" void kernel_launch(void* const* d_in, const int* in_sizes, int n_in,
                              void* d_out, int out_size, void* d_ws, size_t ws_size,
                              hipStream_t stream)
{
    const float* x         = (const float*)d_in[0];
    const float* eps       = (const float*)d_in[1];
    const float* enc_in_w  = (const float*)d_in[2];
    const float* enc_in_b  = (const float*)d_in[3];
    const float* enc_hid_w = (const float*)d_in[4];
    const float* enc_hid_b = (const float*)d_in[5];
    const float* mu_w      = (const float*)d_in[6];
    const float* mu_b      = (const float*)d_in[7];
    const float* lv_w      = (const float*)d_in[8];
    const float* lv_b      = (const float*)d_in[9];
    const float* dec_in_w  = (const float*)d_in[10];
    const float* dec_in_b  = (const float*)d_in[11];
    const float* dec_hid_w = (const float*)d_in[12];
    const float* dec_hid_b = (const float*)d_in[13];
    const float* dec_out_w = (const float*)d_in[14];
    const float* dec_out_b = (const float*)d_in[15];

    const size_t FM = (size_t)Bb * 512 * 2;     // activation fm elems (hi+lo)
    const size_t BZ = (size_t)Bb * 64;

    _Float16* wt  = (_Float16*)d_ws;
    _Float16* xfm = wt + WT_TOTAL;
    _Float16* afm = xfm + FM;
    _Float16* bfm = afm + FM;
    _Float16* zfm = bfm + FM;
    float* fbase  = (float*)(zfm + (size_t)Bb * 64 * 2);
    float* xhat   = fbase;                       // [B,512] fp32
    float* mu_e   = xhat + (size_t)Bb * 512;
    float* lv_e   = mu_e + BZ;
    float* rec8   = lv_e + BZ;                   // [8,B]
    float* best   = rec8 + (size_t)8 * Bb;

    float* out_mu = (float*)d_out;
    float* out_lv = out_mu + (size_t)Bb * Zz;
    float* out_xh = out_lv + (size_t)Bb * Zz;

    const dim3 blk(256);

    // one-time fragment-major weight/x conversion
    fmsplit<true ><<<dim3(8, 8, 8), blk, 0, stream>>>(enc_in_w,           wt + OFF_ENCIN,  512, 512, 262144, PEREXP);
    fmsplit<true ><<<dim3(8, 8, 8), blk, 0, stream>>>(enc_hid_w,          wt + OFF_HID0,   512, 512, 524288, PEREXP);
    fmsplit<true ><<<dim3(8, 8, 8), blk, 0, stream>>>(enc_hid_w + 262144, wt + OFF_HID1,   512, 512, 524288, PEREXP);
    fmsplit<true ><<<dim3(1, 8, 8), blk, 0, stream>>>(mu_w,               wt + OFF_HEADS,  512,  64,  32768, PEREXP);
    fmsplit<true ><<<dim3(1, 8, 8), blk, 0, stream>>>(lv_w,   wt + OFF_HEADS + 65536,      512,  64,  32768, PEREXP);
    fmsplit<true ><<<dim3(8, 1, 8), blk, 0, stream>>>(dec_in_w,           wt + OFF_DECIN,   64, 512,  32768, PEREXP);
    fmsplit<true ><<<dim3(8, 8, 8), blk, 0, stream>>>(dec_hid_w,          wt + OFF_DHID0,  512, 512, 524288, PEREXP);
    fmsplit<true ><<<dim3(8, 8, 8), blk, 0, stream>>>(dec_hid_w + 262144, wt + OFF_DHID1,  512, 512, 524288, PEREXP);
    fmsplit<true ><<<dim3(8, 8, 8), blk, 0, stream>>>(dec_out_w,          wt + OFF_DECOUT, 512, 512, 262144, PEREXP);
    fmsplit<false><<<dim3(256, 8, 1), blk, 0, stream>>>(x,                xfm,             512, 512, 0, 0);

    const dim3 gBig(512), gHead(128), gRow(Bb / 4), gZ(Bb / 64);

    for (int e = 0; e < Eexp; ++e) {
        const _Float16* we = wt + (size_t)e * PEREXP;
        gemm6<512, 0><<<gBig, blk, 0, stream>>>(
            xfm, we + OFF_ENCIN, enc_in_b + (size_t)e * Hh, nullptr,
            nullptr, nullptr, afm, nullptr, nullptr);
        gemm6<512, 0><<<gBig, blk, 0, stream>>>(
            afm, we + OFF_HID0, enc_hid_b + ((size_t)e * 2 + 0) * Hh, nullptr,
            nullptr, nullptr, bfm, nullptr, nullptr);
        gemm6<512, 0><<<gBig, blk, 0, stream>>>(
            bfm, we + OFF_HID1, enc_hid_b + ((size_t)e * 2 + 1) * Hh, nullptr,
            nullptr, nullptr, afm, nullptr, nullptr);
        gemm6<512, 2><<<gHead, blk, 0, stream>>>(
            afm, we + OFF_HEADS, mu_b + (size_t)e * Zz, lv_b + (size_t)e * Zz,
            mu_e, lv_e, nullptr, nullptr, nullptr);
        zfm_kernel<<<gZ, blk, 0, stream>>>(mu_e, lv_e, eps, zfm);
        gemm6< 64, 0><<<gBig, blk, 0, stream>>>(
            zfm, we + OFF_DECIN, dec_in_b + (size_t)e * Hh, nullptr,
            nullptr, nullptr, bfm, nullptr, nullptr);
        gemm6<512, 0><<<gBig, blk, 0, stream>>>(
            bfm, we + OFF_DHID0, dec_hid_b + ((size_t)e * 2 + 0) * Hh, nullptr,
            nullptr, nullptr, afm, nullptr, nullptr);
        gemm6<512, 0><<<gBig, blk, 0, stream>>>(
            afm, we + OFF_DHID1, dec_hid_b + ((size_t)e * 2 + 1) * Hh, nullptr,
            nullptr, nullptr, bfm, nullptr, nullptr);
        gemm6<512, 1><<<gBig, blk, 0, stream>>>(
            bfm, we + OFF_DECOUT, dec_out_b + (size_t)e * Dd, nullptr,
            xhat, nullptr, nullptr, x, rec8);
        select_kernel<<<gRow, blk, 0, stream>>>(
            rec8, best, mu_e, lv_e, xhat, out_mu, out_lv, out_xh, e == 0 ? 1 : 0);
    }
}